// Round 1
// 380.993 us; speedup vs baseline: 1.0160x; 1.0160x over previous
//
#include <hip/hip_runtime.h>

#define RES 64
#define CHANNEL 32
#define DIM 512
#define BATCH 32
#define ROWS (RES * RES * CHANNEL)   // 131072

typedef unsigned short u16;
typedef float f32x4v __attribute__((ext_vector_type(4)));
typedef short bf16x8 __attribute__((ext_vector_type(8)));   // 8 bf16 = 4 VGPR

__device__ __forceinline__ uint32_t bf16_rne_bits(float x) {
    // round-to-nearest-even fp32 -> bf16, result in top 16 bits
    uint32_t u = __float_as_uint(x);
    return u + 0x7fffu + ((u >> 16) & 1u);
}

// Writes the scale table L[d]*style[b][d] as bf16 hi/lo, pre-arranged in the
// MFMA A-fragment layout so eigen can load fragments as one dwordx4 per lane.
// Layout (u16 units): tab[kc:16][nt:2][hl:2][lane:64][j:8]
//   where d = kc*32 + (lane>>4)*8 + j,  b = nt*16 + (lane&15)
__global__ void scale_pack_kernel(const float* __restrict__ style,
                                  const float* __restrict__ L,
                                  u16* __restrict__ tab) {
    int i = blockIdx.x * 256 + threadIdx.x;   // 0 .. 16383
    int d = i >> 5;
    int b = i & 31;
    float s = L[d] * style[b * DIM + d];
    uint32_t t = bf16_rne_bits(s);
    u16 hi = (u16)(t >> 16);
    float hf = __uint_as_float(t & 0xffff0000u);
    float lf = s - hf;
    u16 lo = (u16)(bf16_rne_bits(lf) >> 16);

    int kc = d >> 5, kg = (d >> 3) & 3, j = d & 7;
    int nt = b >> 4, lc = b & 15;
    int base = kc * 2048 + nt * 1024 + (kg * 16 + lc) * 8 + j;
    tab[base]       = hi;   // hl = 0
    tab[base + 512] = lo;   // hl = 1
}

__device__ __forceinline__ void cvt_hl(const float4& p, const float4& q,
                                       bf16x8& h, bf16x8& l) {
    float x[8] = {p.x, p.y, p.z, p.w, q.x, q.y, q.z, q.w};
#pragma unroll
    for (int j = 0; j < 8; ++j) {
        uint32_t t = bf16_rne_bits(x[j]);
        h[j] = (short)(t >> 16);
        float hf = __uint_as_float(t & 0xffff0000u);
        l[j] = (short)(bf16_rne_bits(x[j] - hf) >> 16);
    }
}

// One wave owns 32 rows x 32 batches. out[b][row] = sum_d U[row][d]*s[d][b] + mu[row]
// computed as 3-term bf16-split MFMA: Uh*sh + Ul*sh + Uh*sl  (Ul*sl ~ 2^-18, dropped).
// Operand order mfma(A=s_frag, B=u_frag) so D: row=(lane>>4)*4+reg -> batch,
// col=lane&15 -> U-row  => stores are 64B-coalesced along the row dimension.
__global__ __launch_bounds__(256) void eigen_mfma_kernel(
    const float* __restrict__ U,
    const float* __restrict__ mu,
    const u16* __restrict__ tab,
    float* __restrict__ out) {

    const int tid  = threadIdx.x;
    const int wid  = tid >> 6;
    const int lane = tid & 63;
    const int lc   = lane & 15;
    const int kg   = lane >> 4;

    const int m0 = blockIdx.x * 128 + wid * 32;

    // per-lane U pointers: row m0+msub*16+lc, k-group kg (8 floats = 2 float4)
    const float4* __restrict__ a0 = (const float4*)(U + (size_t)(m0 + lc) * DIM + kg * 8);
    const float4* __restrict__ a1 = (const float4*)(U + (size_t)(m0 + 16 + lc) * DIM + kg * 8);
    const u16* __restrict__ bp = tab + lane * 8;

    f32x4v acc00 = {0.f, 0.f, 0.f, 0.f};   // [msub0][nt0]
    f32x4v acc01 = acc00;                   // [msub0][nt1]
    f32x4v acc10 = acc00;                   // [msub1][nt0]
    f32x4v acc11 = acc00;                   // [msub1][nt1]

    // prologue: load kc = 0
    float4 c0a = a0[0], c0b = a0[1], c1a = a1[0], c1b = a1[1];
    bf16x8 bh0 = *(const bf16x8*)(bp);
    bf16x8 bl0 = *(const bf16x8*)(bp + 512);
    bf16x8 bh1 = *(const bf16x8*)(bp + 1024);
    bf16x8 bl1 = *(const bf16x8*)(bp + 1536);

#pragma unroll 1
    for (int kc = 0; kc < DIM / 32; ++kc) {   // 16 K-chunks
        float4 n0a, n0b, n1a, n1b;
        bf16x8 nh0, nl0, nh1, nl1;
        if (kc < 15) {
            const int o = (kc + 1) * 8;       // float4 stride per K-chunk
            n0a = a0[o];     n0b = a0[o + 1];
            n1a = a1[o];     n1b = a1[o + 1];
            const u16* nb = bp + (kc + 1) * 2048;
            nh0 = *(const bf16x8*)(nb);
            nl0 = *(const bf16x8*)(nb + 512);
            nh1 = *(const bf16x8*)(nb + 1024);
            nl1 = *(const bf16x8*)(nb + 1536);
        }

        bf16x8 uh0, ul0, uh1, ul1;
        cvt_hl(c0a, c0b, uh0, ul0);
        cvt_hl(c1a, c1b, uh1, ul1);

        // term 1: Uh * sh
        acc00 = __builtin_amdgcn_mfma_f32_16x16x32_bf16(bh0, uh0, acc00, 0, 0, 0);
        acc10 = __builtin_amdgcn_mfma_f32_16x16x32_bf16(bh0, uh1, acc10, 0, 0, 0);
        acc01 = __builtin_amdgcn_mfma_f32_16x16x32_bf16(bh1, uh0, acc01, 0, 0, 0);
        acc11 = __builtin_amdgcn_mfma_f32_16x16x32_bf16(bh1, uh1, acc11, 0, 0, 0);
        // term 2: Uh * sl
        acc00 = __builtin_amdgcn_mfma_f32_16x16x32_bf16(bl0, uh0, acc00, 0, 0, 0);
        acc10 = __builtin_amdgcn_mfma_f32_16x16x32_bf16(bl0, uh1, acc10, 0, 0, 0);
        acc01 = __builtin_amdgcn_mfma_f32_16x16x32_bf16(bl1, uh0, acc01, 0, 0, 0);
        acc11 = __builtin_amdgcn_mfma_f32_16x16x32_bf16(bl1, uh1, acc11, 0, 0, 0);
        // term 3: Ul * sh
        acc00 = __builtin_amdgcn_mfma_f32_16x16x32_bf16(bh0, ul0, acc00, 0, 0, 0);
        acc10 = __builtin_amdgcn_mfma_f32_16x16x32_bf16(bh0, ul1, acc10, 0, 0, 0);
        acc01 = __builtin_amdgcn_mfma_f32_16x16x32_bf16(bh1, ul0, acc01, 0, 0, 0);
        acc11 = __builtin_amdgcn_mfma_f32_16x16x32_bf16(bh1, ul1, acc11, 0, 0, 0);

        if (kc < 15) {
            c0a = n0a; c0b = n0b; c1a = n1a; c1b = n1b;
            bh0 = nh0; bl0 = nl0; bh1 = nh1; bl1 = nl1;
        }
    }

    // epilogue: D row = batch-in-tile = kg*4 + r, D col = U-row-in-tile = lc
    const float mu0 = mu[m0 + lc];
    const float mu1 = mu[m0 + 16 + lc];
    const size_t col0 = (size_t)(m0 + lc);
    const size_t col1 = (size_t)(m0 + 16 + lc);
#pragma unroll
    for (int r = 0; r < 4; ++r) {
        out[(size_t)(kg * 4 + r) * ROWS + col0]        = acc00[r] + mu0;
        out[(size_t)(kg * 4 + r) * ROWS + col1]        = acc10[r] + mu1;
        out[(size_t)(16 + kg * 4 + r) * ROWS + col0]   = acc01[r] + mu0;
        out[(size_t)(16 + kg * 4 + r) * ROWS + col1]   = acc11[r] + mu1;
    }
}

extern "C" void kernel_launch(void* const* d_in, const int* in_sizes, int n_in,
                              void* d_out, int out_size, void* d_ws, size_t ws_size,
                              hipStream_t stream) {
    const float* style = (const float*)d_in[0];   // [32, 512]
    const float* U     = (const float*)d_in[1];   // [64, 64, 32, 512]
    const float* L     = (const float*)d_in[2];   // [512]
    const float* mu    = (const float*)d_in[3];   // [64, 64, 32]
    float* out = (float*)d_out;                   // [32, 64, 64, 32]
    u16* tab = (u16*)d_ws;                        // 32768 u16 = 64 KiB

    scale_pack_kernel<<<64, 256, 0, stream>>>(style, L, tab);
    eigen_mfma_kernel<<<ROWS / 128, 256, 0, stream>>>(U, mu, tab, out);
}

// Round 2
// 374.261 us; speedup vs baseline: 1.0343x; 1.0180x over previous
//
#include <hip/hip_runtime.h>

#define RES 64
#define CHANNEL 32
#define DIM 512
#define BATCH 32
#define ROWS (RES * RES * CHANNEL)   // 131072

typedef unsigned short u16;
typedef float f32x4v __attribute__((ext_vector_type(4)));
typedef short bf16x8 __attribute__((ext_vector_type(8)));   // 8 bf16 = 4 VGPR

__device__ __forceinline__ uint32_t bf16_rne_bits(float x) {
    // round-to-nearest-even fp32 -> bf16, result in top 16 bits
    uint32_t u = __float_as_uint(x);
    return u + 0x7fffu + ((u >> 16) & 1u);
}

// Writes the scale table L[d]*style[b][d] as bf16 hi/lo, pre-arranged in the
// MFMA A-fragment layout so eigen can load fragments as one dwordx4 per lane.
// Layout (u16 units): tab[kc:16][nt:2][hl:2][lane:64][j:8]
//   where d = kc*32 + (lane>>4)*8 + j,  b = nt*16 + (lane&15)
__global__ void scale_pack_kernel(const float* __restrict__ style,
                                  const float* __restrict__ L,
                                  u16* __restrict__ tab) {
    int i = blockIdx.x * 256 + threadIdx.x;   // 0 .. 16383
    int d = i >> 5;
    int b = i & 31;
    float s = L[d] * style[b * DIM + d];
    uint32_t t = bf16_rne_bits(s);
    u16 hi = (u16)(t >> 16);
    float hf = __uint_as_float(t & 0xffff0000u);
    float lf = s - hf;
    u16 lo = (u16)(bf16_rne_bits(lf) >> 16);

    int kc = d >> 5, kg = (d >> 3) & 3, j = d & 7;
    int nt = b >> 4, lc = b & 15;
    int base = kc * 2048 + nt * 1024 + (kg * 16 + lc) * 8 + j;
    tab[base]       = hi;   // hl = 0
    tab[base + 512] = lo;   // hl = 1
}

// trunc-split: hi = trunc-to-bf16(x), lo = rne-bf16(x - hi).
// lo captures the truncation remainder exactly, so pair accuracy ~2^-17 rel,
// same as RNE-split, at ~6 VALU ops/element instead of ~10.
__device__ __forceinline__ void cvt_hl(const float4& p, const float4& q,
                                       bf16x8& h, bf16x8& l) {
    float x[8] = {p.x, p.y, p.z, p.w, q.x, q.y, q.z, q.w};
#pragma unroll
    for (int j = 0; j < 8; ++j) {
        uint32_t u = __float_as_uint(x[j]);
        h[j] = (short)(u >> 16);
        float lf = x[j] - __uint_as_float(u & 0xffff0000u);
        l[j] = (short)(bf16_rne_bits(lf) >> 16);
    }
}

// One wave owns 32 rows x 32 batches. out[b][row] = sum_d U[row][d]*s[d][b] + mu[row]
// 3-term bf16-split MFMA: Uh*sh + Ul*sh + Uh*sl  (Ul*sl ~ 2^-18, dropped).
// Operand order mfma(A=s_frag, B=u_frag) so D: row=(lane>>4)*4+reg -> batch,
// col=lane&15 -> U-row  => stores are 64B-coalesced along the row dimension.
// __launch_bounds__(256,4): force <=128 VGPR -> 4 waves/SIMD (occupancy cliff at 128).
__global__ __launch_bounds__(256, 4) void eigen_mfma_kernel(
    const float* __restrict__ U,
    const float* __restrict__ mu,
    const u16* __restrict__ tab,
    float* __restrict__ out) {

    const int tid  = threadIdx.x;
    const int wid  = tid >> 6;
    const int lane = tid & 63;
    const int lc   = lane & 15;
    const int kg   = lane >> 4;

    const int m0 = blockIdx.x * 128 + wid * 32;

    // per-lane U pointers: row m0+msub*16+lc, k-group kg (8 floats = 2 float4)
    const float4* __restrict__ a0 = (const float4*)(U + (size_t)(m0 + lc) * DIM + kg * 8);
    const float4* __restrict__ a1 = (const float4*)(U + (size_t)(m0 + 16 + lc) * DIM + kg * 8);
    const u16* __restrict__ bp = tab + lane * 8;

    // hoist mu loads: issue early, consumed only in the epilogue
    const float mu0 = mu[m0 + lc];
    const float mu1 = mu[m0 + 16 + lc];

    f32x4v acc00 = {0.f, 0.f, 0.f, 0.f};   // [msub0][nt0]
    f32x4v acc01 = acc00;                   // [msub0][nt1]
    f32x4v acc10 = acc00;                   // [msub1][nt0]
    f32x4v acc11 = acc00;                   // [msub1][nt1]

    // prologue: load U for kc = 0
    float4 c0a = a0[0], c0b = a0[1], c1a = a1[0], c1b = a1[1];

#pragma unroll 1
    for (int kc = 0; kc < DIM / 16; ++kc) {   // 16 K-chunks (DIM/32)
        if (kc >= DIM / 32) break;            // keep literal loop shape simple
        // tab fragments for CURRENT chunk: L2-hot (~200cy), covered by cvt issue + TLP
        const u16* tb = bp + kc * 2048;
        bf16x8 bh0 = *(const bf16x8*)(tb);
        bf16x8 bl0 = *(const bf16x8*)(tb + 512);
        bf16x8 bh1 = *(const bf16x8*)(tb + 1024);
        bf16x8 bl1 = *(const bf16x8*)(tb + 1536);

        // 1-deep prefetch of next U chunk
        float4 n0a, n0b, n1a, n1b;
        if (kc < 15) {
            const int o = (kc + 1) * 8;       // float4 stride per K-chunk
            n0a = a0[o];     n0b = a0[o + 1];
            n1a = a1[o];     n1b = a1[o + 1];
        }

        bf16x8 uh0, ul0, uh1, ul1;
        cvt_hl(c0a, c0b, uh0, ul0);
        cvt_hl(c1a, c1b, uh1, ul1);

        // term 1: Uh * sh
        acc00 = __builtin_amdgcn_mfma_f32_16x16x32_bf16(bh0, uh0, acc00, 0, 0, 0);
        acc10 = __builtin_amdgcn_mfma_f32_16x16x32_bf16(bh0, uh1, acc10, 0, 0, 0);
        acc01 = __builtin_amdgcn_mfma_f32_16x16x32_bf16(bh1, uh0, acc01, 0, 0, 0);
        acc11 = __builtin_amdgcn_mfma_f32_16x16x32_bf16(bh1, uh1, acc11, 0, 0, 0);
        // term 2: Uh * sl
        acc00 = __builtin_amdgcn_mfma_f32_16x16x32_bf16(bl0, uh0, acc00, 0, 0, 0);
        acc10 = __builtin_amdgcn_mfma_f32_16x16x32_bf16(bl0, uh1, acc10, 0, 0, 0);
        acc01 = __builtin_amdgcn_mfma_f32_16x16x32_bf16(bl1, uh0, acc01, 0, 0, 0);
        acc11 = __builtin_amdgcn_mfma_f32_16x16x32_bf16(bl1, uh1, acc11, 0, 0, 0);
        // term 3: Ul * sh
        acc00 = __builtin_amdgcn_mfma_f32_16x16x32_bf16(bh0, ul0, acc00, 0, 0, 0);
        acc10 = __builtin_amdgcn_mfma_f32_16x16x32_bf16(bh0, ul1, acc10, 0, 0, 0);
        acc01 = __builtin_amdgcn_mfma_f32_16x16x32_bf16(bh1, ul0, acc01, 0, 0, 0);
        acc11 = __builtin_amdgcn_mfma_f32_16x16x32_bf16(bh1, ul1, acc11, 0, 0, 0);

        if (kc < 15) {
            c0a = n0a; c0b = n0b; c1a = n1a; c1b = n1b;
        }
    }

    // epilogue: D row = batch-in-tile = kg*4 + r, D col = U-row-in-tile = lc
    const size_t col0 = (size_t)(m0 + lc);
    const size_t col1 = (size_t)(m0 + 16 + lc);
#pragma unroll
    for (int r = 0; r < 4; ++r) {
        out[(size_t)(kg * 4 + r) * ROWS + col0]        = acc00[r] + mu0;
        out[(size_t)(kg * 4 + r) * ROWS + col1]        = acc10[r] + mu1;
        out[(size_t)(16 + kg * 4 + r) * ROWS + col0]   = acc01[r] + mu0;
        out[(size_t)(16 + kg * 4 + r) * ROWS + col1]   = acc11[r] + mu1;
    }
}

extern "C" void kernel_launch(void* const* d_in, const int* in_sizes, int n_in,
                              void* d_out, int out_size, void* d_ws, size_t ws_size,
                              hipStream_t stream) {
    const float* style = (const float*)d_in[0];   // [32, 512]
    const float* U     = (const float*)d_in[1];   // [64, 64, 32, 512]
    const float* L     = (const float*)d_in[2];   // [512]
    const float* mu    = (const float*)d_in[3];   // [64, 64, 32]
    float* out = (float*)d_out;                   // [32, 64, 64, 32]
    u16* tab = (u16*)d_ws;                        // 32768 u16 = 64 KiB

    scale_pack_kernel<<<64, 256, 0, stream>>>(style, L, tab);
    eigen_mfma_kernel<<<ROWS / 128, 256, 0, stream>>>(U, mu, tab, out);
}